// Round 10
// baseline (426.627 us; speedup 1.0000x reference)
//
#include <hip/hip_runtime.h>

typedef __bf16 bf16_t;
typedef __bf16 bf16x4 __attribute__((ext_vector_type(4)));
typedef __bf16 bf16x8 __attribute__((ext_vector_type(8)));
typedef short s16x4 __attribute__((ext_vector_type(4)));
typedef float f32x4 __attribute__((ext_vector_type(4)));

#define BN_EPS 1e-3f

#define GLOAD_LDS16(g, l) \
  __builtin_amdgcn_global_load_lds((const __attribute__((address_space(1))) void*)(g), \
                                   (__attribute__((address_space(3))) void*)(l), 16, 0, 0)

// =============== prep: cvt + all 3 weight transposes in ONE launch ===============
// (R8, unchanged)
__global__ __launch_bounds__(256) void prep(
    const float* __restrict__ x, bf16_t* __restrict__ xb,
    const float* __restrict__ Wkv, bf16_t* __restrict__ outK, bf16_t* __restrict__ outV,
    const float* __restrict__ Wq, bf16_t* __restrict__ Wq_t,
    const float* __restrict__ Wp, bf16_t* __restrict__ Wp_t)
{
  __shared__ bf16_t t[32][33];
  const int id = blockIdx.x;
  if (id < 4096) {
    long i = ((long)id * 256 + threadIdx.x) * 8;
    f32x4 a = *(const f32x4*)(x + i);
    f32x4 b = *(const f32x4*)(x + i + 4);
    bf16x8 o;
    o[0] = (bf16_t)a[0]; o[1] = (bf16_t)a[1]; o[2] = (bf16_t)a[2]; o[3] = (bf16_t)a[3];
    o[4] = (bf16_t)b[0]; o[5] = (bf16_t)b[1]; o[6] = (bf16_t)b[2]; o[7] = (bf16_t)b[3];
    *(bf16x8*)(xb + i) = o;
    return;
  }
  const int tx = threadIdx.x & 31, ty = threadIdx.x >> 5;
  if (id < 4256) {                       // Wkv split-transpose [256][640]
    int id2 = id - 4096;
    int bx = (id2 % 20) * 32, by = (id2 / 20) * 32;
#pragma unroll
    for (int i = 0; i < 32; i += 8)
      t[ty + i][tx] = (bf16_t)Wkv[(long)(by + ty + i) * 640 + (bx + tx)];
    __syncthreads();
#pragma unroll
    for (int i = 0; i < 32; i += 8) {
      int c = bx + ty + i;
      int h = c / 80, r80 = c - h * 80;
      bf16_t v = t[tx][ty + i];
      if (r80 < 16)
        outK[(long)(h * 16 + r80) * 256 + (by + tx)] = v;
      else
        outV[(long)(h * 64 + (r80 - 16)) * 256 + (by + tx)] = v;
    }
  } else if (id < 4288) {                // Wq transpose: fp32 [256][128] -> [128][256]
    int id3 = id - 4256;
    int bx = (id3 & 3) * 32, by = (id3 >> 2) * 32;
#pragma unroll
    for (int i = 0; i < 32; i += 8)
      t[ty + i][tx] = (bf16_t)Wq[(long)(by + ty + i) * 128 + (bx + tx)];
    __syncthreads();
#pragma unroll
    for (int i = 0; i < 32; i += 8)
      Wq_t[(long)(bx + ty + i) * 256 + (by + tx)] = t[tx][ty + i];
  } else {                               // Wp transpose: fp32 [512][512] -> [512][512]
    int id4 = id - 4288;
    int bx = (id4 & 15) * 32, by = (id4 >> 4) * 32;
#pragma unroll
    for (int i = 0; i < 32; i += 8)
      t[ty + i][tx] = (bf16_t)Wp[(long)(by + ty + i) * 512 + (bx + tx)];
    __syncthreads();
#pragma unroll
    for (int i = 0; i < 32; i += 8)
      Wp_t[(long)(bx + ty + i) * 512 + (by + tx)] = t[tx][ty + i];
  }
}

// =============== fused QKV projection GEMM: x[32768,256] @ Wf[768,256]^T ===============
// (R6, unchanged)
__global__ __launch_bounds__(512, 1) void qkv_fused(
    const bf16_t* __restrict__ xb, const bf16_t* __restrict__ Wf,
    const float* __restrict__ bkv, const float* __restrict__ g_kv,
    const float* __restrict__ b_kv, const float* __restrict__ m_kv,
    const float* __restrict__ v_kv,
    const float* __restrict__ bq, const float* __restrict__ g_q,
    const float* __restrict__ b_q, const float* __restrict__ m_q,
    const float* __restrict__ v_q,
    bf16_t* __restrict__ Kbuf, bf16_t* __restrict__ Vtb, bf16_t* __restrict__ Qbuf)
{
  __shared__ __align__(16) char Xs[65536];   // [128 rows][256 k] bf16, swizzled units
  __shared__ __align__(16) char Ws[65536];   // [128 rows][256 k] bf16, swizzled units

  const int tid = threadIdx.x;
  const int lane = tid & 63, w = tid >> 6;        // 8 waves
  const int quad = lane >> 4, l15 = lane & 15;
  const int wm = w >> 2, wn = w & 3;              // wave grid 2x4

  const int id = blockIdx.x;
  const int xcd = id & 7, slot = id >> 3;         // slot 0..191
  const int sd6 = slot / 6;
  const int mt = xcd * 32 + sd6;                  // 0..255 (contiguous per XCD)
  const int nt = slot - sd6 * 6;                  // 0..5
  const int blockM = mt * 128, blockN = nt * 128;

  {
    const int r_lo = w * 2 + (lane >> 5);                 // row within 16-row round
    const int soff = ((lane & 31) ^ (r_lo & 7)) << 4;     // swizzled source byte in row
#pragma unroll
    for (int rnd = 0; rnd < 8; rnd++) {
      const int row = rnd * 16 + r_lo;
      GLOAD_LDS16((const char*)xb + (long)(blockM + row) * 512 + soff,
                  &Xs[rnd * 8192 + w * 1024]);
      GLOAD_LDS16((const char*)Wf + (long)(blockN + row) * 512 + soff,
                  &Ws[rnd * 8192 + w * 1024]);
    }
  }
  __syncthreads();

  const int sw = l15 & 7;
  f32x4 acc[4][2] = {};
#pragma unroll
  for (int ks = 0; ks < 8; ks++) {
    const int u = ks * 4 + quad;
    const int su = (u ^ sw) << 4;
    bf16x8 af[4];
#pragma unroll
    for (int mi = 0; mi < 4; mi++)
      af[mi] = *(const bf16x8*)(&Xs[(wm * 64 + mi * 16 + l15) * 512 + su]);
    bf16x8 bf_[2];
#pragma unroll
    for (int ni = 0; ni < 2; ni++)
      bf_[ni] = *(const bf16x8*)(&Ws[(wn * 32 + ni * 16 + l15) * 512 + su]);
#pragma unroll
    for (int mi = 0; mi < 4; mi++)
#pragma unroll
      for (int ni = 0; ni < 2; ni++)
        acc[mi][ni] = __builtin_amdgcn_mfma_f32_16x16x32_bf16(af[mi], bf_[ni], acc[mi][ni], 0, 0, 0);
  }

#pragma unroll
  for (int ni = 0; ni < 2; ni++) {
    const int nfbase = blockN + wn * 32 + ni * 16;
    const int col = nfbase + l15;
    float s, t, bia;
    if (nfbase < 128) {            // K channels
      int cp = (col >> 4) * 80 + (col & 15);
      s = g_kv[cp] / sqrtf(v_kv[cp] + BN_EPS);
      t = b_kv[cp] - m_kv[cp] * s;
      bia = bkv[cp];
      int h = col >> 4, d = col & 15;
#pragma unroll
      for (int mi = 0; mi < 4; mi++)
#pragma unroll
        for (int r = 0; r < 4; r++) {
          int grow = blockM + wm * 64 + mi * 16 + quad * 4 + r;
          int b = grow >> 12, seq = grow & 4095;
          float y = (acc[mi][ni][r] + bia) * s + t;
          Kbuf[((long)((b * 8 + h) * 4096 + seq)) * 16 + d] = (bf16_t)y;
        }
    } else if (nfbase < 640) {     // V channels -> interleaved Vt
      int ch = col - 128;
      int cp = (ch >> 6) * 80 + 16 + (ch & 63);
      s = g_kv[cp] / sqrtf(v_kv[cp] + BN_EPS);
      t = b_kv[cp] - m_kv[cp] * s;
      bia = bkv[cp];
      int h2 = ch >> 6, dv = ch & 63;
#pragma unroll
      for (int mi = 0; mi < 4; mi++)
#pragma unroll
        for (int r = 0; r < 4; r++) {
          int grow = blockM + wm * 64 + mi * 16 + quad * 4 + r;
          int b = grow >> 12, seq = grow & 4095;
          int kb = seq >> 5, s32 = seq & 31;
          int qd = (s32 & 15) >> 2, j = (s32 >> 4) * 4 + (s32 & 3);
          float y = (acc[mi][ni][r] + bia) * s + t;
          Vtb[(((long)(b * 8 + h2)) << 18) + (kb << 11) + (qd << 9) + (dv << 3) + j] = (bf16_t)y;
        }
    } else {                        // Q channels (strided-subsampled rows only)
      int qc = col - 640;
      s = g_q[qc] / sqrtf(v_q[qc] + BN_EPS);
      t = b_q[qc] - m_q[qc] * s;
      bia = bq[qc];
      int h = qc >> 4, d = qc & 15;
#pragma unroll
      for (int mi = 0; mi < 4; mi++) {
        if ((((blockM + wm * 64 + mi * 16) >> 6) & 1) != 0) continue;
#pragma unroll
        for (int r = 0; r < 4; r += 2) {
          int grow = blockM + wm * 64 + mi * 16 + quad * 4 + r;
          int b = grow >> 12, seq = grow & 4095;
          int qp = ((seq >> 7) << 5) + ((seq & 63) >> 1);
          float y = (acc[mi][ni][r] + bia) * s + t;
          Qbuf[((long)((b * 8 + h) * 1024 + qp)) * 16 + d] = (bf16_t)(y * 0.36067376f);
        }
      }
    }
  }
}

// =============== fused output projection: outp[8192,512] @ WpT[512,512]^T + BN ===============
// (R7, unchanged)
__global__ __launch_bounds__(512, 1) void proj_fused(
    const bf16_t* __restrict__ A, const bf16_t* __restrict__ Wt,
    const float* __restrict__ bias, const float* __restrict__ gamma,
    const float* __restrict__ beta, const float* __restrict__ mean,
    const float* __restrict__ var, float* __restrict__ outf)
{
  __shared__ __align__(16) char Xs[65536];
  __shared__ __align__(16) char Wl[65536];

  const int tid = threadIdx.x;
  const int lane = tid & 63, w = tid >> 6;
  const int quad = lane >> 4, l15 = lane & 15;
  const int wm = w >> 2, wn = w & 3;

  const int id = blockIdx.x;
  const int xcd = id & 7, slot = id >> 3;
  const int mt = xcd * 8 + (slot >> 2);
  const int nt = slot & 3;
  const int blockM = mt * 128, blockN = nt * 128;

  const int r_lo = w * 2 + (lane >> 5);
  const int soff = ((lane & 31) ^ (r_lo & 7)) << 4;
  const int sw = l15 & 7;
  f32x4 acc[4][2] = {};

#pragma unroll
  for (int kc = 0; kc < 2; kc++) {
    if (kc) __syncthreads();
#pragma unroll
    for (int rnd = 0; rnd < 8; rnd++) {
      const int row = rnd * 16 + r_lo;
      GLOAD_LDS16((const char*)A  + (long)(blockM + row) * 1024 + kc * 512 + soff,
                  &Xs[rnd * 8192 + w * 1024]);
      GLOAD_LDS16((const char*)Wt + (long)(blockN + row) * 1024 + kc * 512 + soff,
                  &Wl[rnd * 8192 + w * 1024]);
    }
    __syncthreads();

#pragma unroll
    for (int ks = 0; ks < 8; ks++) {
      const int u = ks * 4 + quad;
      const int su = (u ^ sw) << 4;
      bf16x8 af[4];
#pragma unroll
      for (int mi = 0; mi < 4; mi++)
        af[mi] = *(const bf16x8*)(&Xs[(wm * 64 + mi * 16 + l15) * 512 + su]);
      bf16x8 bw[2];
#pragma unroll
      for (int ni = 0; ni < 2; ni++)
        bw[ni] = *(const bf16x8*)(&Wl[(wn * 32 + ni * 16 + l15) * 512 + su]);
#pragma unroll
      for (int mi = 0; mi < 4; mi++)
#pragma unroll
        for (int ni = 0; ni < 2; ni++)
          acc[mi][ni] = __builtin_amdgcn_mfma_f32_16x16x32_bf16(af[mi], bw[ni], acc[mi][ni], 0, 0, 0);
    }
  }

#pragma unroll
  for (int ni = 0; ni < 2; ni++) {
    int col = blockN + wn * 32 + ni * 16 + l15;
    float s = gamma[col] / sqrtf(var[col] + BN_EPS);
    float t = beta[col] - mean[col] * s;
    float bia = bias[col];
#pragma unroll
    for (int mi = 0; mi < 4; mi++)
#pragma unroll
      for (int r = 0; r < 4; r++) {
        int grow = blockM + wm * 64 + mi * 16 + quad * 4 + r;
        float y = (acc[mi][ni][r] + bia) * s + t;
        outf[(long)grow * 512 + col] = y;
      }
  }
}

// ---------------- flash attention + ABLATION instantiations (R10 diagnostic round) ----------------
// R9 regressed (66->73: fewer waves/SIMD lost latency hiding; phase-batch raised VGPR 60->88).
// Pre-commit triggered: R6/R7/R8 all ~66 us under 2x swings in waves, LDS traffic, prefetch
// depth -> partition the wall EMPIRICALLY before touching structure again.
//   ABL=0: exact R8 kernel (66 us best) -- the real one, writes outp.          NT=64
//   ABL=1: stage-only (staging + counted vmcnt + barriers, compute deleted).   NT=256 (4x)
//   ABL=2: compute-only (barriers + ds_read->QK->exp->PV; no staging/waits;    NT=256 (4x)
//          O/lpacc kept alive via empty-asm sinks, rule 17; reads whatever LDS holds --
//          bit-patterns are timing-neutral for VALU/MFMA).
// Readout: ABL=2 expected to dominate top-5 (FETCH ~0 disambiguates); ABL=1 recovered from
// Delta-total. Rule-19 caveat: co-compilation may shift ABL=0 a few %.
template <int ABL>
__global__ __launch_bounds__(256, 2) void attn_abl(
    const bf16_t* __restrict__ Q, const bf16_t* __restrict__ K,
    const bf16_t* __restrict__ Vt, bf16_t* __restrict__ outp)
{
  constexpr int NT = (ABL == 0) ? 64 : 256;
  const int tid = threadIdx.x;
  const int lane = tid & 63, w = tid >> 6;                // 4 waves
  const int quad = lane >> 4, l15 = lane & 15;
  const int bh = blockIdx.x & 63, qb = blockIdx.x >> 6;   // qb 0..7
  const int b = bh >> 3, h = bh & 7;
  const bf16_t* Qp = Q + (long)bh * 1024 * 16;
  const char* Kg = (const char*)(K + (long)bh * 4096 * 16);     // [key][16d], 32 B/row
  const char* Vg = (const char*)(Vt + ((long)bh << 18));        // interleaved, 512 KB/bh

  __shared__ __align__(16) char Kl[4][2048];
  __shared__ __align__(16) char Vl[4][8192];

  const int q0 = qb * 128 + w * 32;
  bf16x8 qB8[2];
#pragma unroll
  for (int g = 0; g < 2; g++) {
    bf16x8 qv = *(const bf16x8*)(Qp + (long)(q0 + g * 16 + l15) * 16 + (quad & 1) * 8);
    bf16x8 zq = {};
    qB8[g] = (quad < 2) ? qv : zq;
  }

  f32x4 O[2][4] = {};        // [qgroup][dv tile]: lane holds (q=l15, dv=dt*16+quad*4+r)
  f32x4 lpacc[2] = {};       // ones-MFMA: every row = sum_k P[k][q=l15]
  const f32x4 zf = {0.f, 0.f, 0.f, 0.f};

  bf16x8 ones8;
#pragma unroll
  for (int i = 0; i < 8; i++) ones8[i] = (bf16_t)1.f;

  const char* vsrc = Vg + (long)lane * 16;
  const char* ksrc = Kg + (long)lane * 32 + (w - 2) * 16;

  auto stage = [&](int t, int buf) {
    if (w < 2) {
#pragma unroll
      for (int c = 0; c < 2; c++)
        GLOAD_LDS16(vsrc + (long)t * 8192 + (w * 2 + c) * 1024, &Vl[buf][(w * 2 + c) * 1024]);
    } else {
#pragma unroll
      for (int c = 0; c < 2; c++)
        GLOAD_LDS16(vsrc + (long)t * 8192 + ((w - 2) * 2 + 4 + c) * 1024,
                    &Vl[buf][((w - 2) * 2 + 4 + c) * 1024]);
      GLOAD_LDS16(ksrc + (long)t * 2048, &Kl[buf][(w - 2) * 1024]);
    }
  };

  const int krow_off = (quad & 1) * 1024;

  auto compute = [&](int buf) {
#pragma unroll
    for (int kh = 0; kh < 2; kh++) {
      bf16x8 k0 = *(const bf16x8*)(&Kl[buf][krow_off + (kh * 32 + l15) * 16]);
      bf16x8 k1 = *(const bf16x8*)(&Kl[buf][krow_off + (kh * 32 + 16 + l15) * 16]);
      bf16x8 vA[4];
#pragma unroll
      for (int dt = 0; dt < 4; dt++)
        vA[dt] = *(const bf16x8*)(&Vl[buf][kh * 4096 + quad * 1024 + (dt * 16 + l15) * 16]);
#pragma unroll
      for (int g = 0; g < 2; g++) {
        f32x4 S0 = __builtin_amdgcn_mfma_f32_16x16x32_bf16(k0, qB8[g], zf, 0, 0, 0);
        f32x4 S1 = __builtin_amdgcn_mfma_f32_16x16x32_bf16(k1, qB8[g], zf, 0, 0, 0);
        bf16x8 pb;
        pb[0] = (bf16_t)__builtin_amdgcn_exp2f(S0[0]);
        pb[1] = (bf16_t)__builtin_amdgcn_exp2f(S0[1]);
        pb[2] = (bf16_t)__builtin_amdgcn_exp2f(S0[2]);
        pb[3] = (bf16_t)__builtin_amdgcn_exp2f(S0[3]);
        pb[4] = (bf16_t)__builtin_amdgcn_exp2f(S1[0]);
        pb[5] = (bf16_t)__builtin_amdgcn_exp2f(S1[1]);
        pb[6] = (bf16_t)__builtin_amdgcn_exp2f(S1[2]);
        pb[7] = (bf16_t)__builtin_amdgcn_exp2f(S1[3]);
        lpacc[g] = __builtin_amdgcn_mfma_f32_16x16x32_bf16(ones8, pb, lpacc[g], 0, 0, 0);
#pragma unroll
        for (int dt = 0; dt < 4; dt++)
          O[g][dt] = __builtin_amdgcn_mfma_f32_16x16x32_bf16(vA[dt], pb, O[g][dt], 0, 0, 0);
      }
    }
  };

  if constexpr (ABL != 2) {
    stage(0, 0);
    stage(1, 1);
    stage(2, 2);
  }
#pragma unroll 4
  for (int t = 0; t < NT; t++) {
    if constexpr (ABL != 2) {
      if (t + 2 < NT) {              // tiles t+1, t+2 may stay in flight
        if (w < 2) asm volatile("s_waitcnt vmcnt(4)" ::: "memory");
        else       asm volatile("s_waitcnt vmcnt(6)" ::: "memory");
      } else if (t + 1 < NT) {
        if (w < 2) asm volatile("s_waitcnt vmcnt(2)" ::: "memory");
        else       asm volatile("s_waitcnt vmcnt(3)" ::: "memory");
      } else {
        asm volatile("s_waitcnt vmcnt(0)" ::: "memory");
      }
    }
    __builtin_amdgcn_s_barrier();
    __builtin_amdgcn_sched_barrier(0);
    if constexpr (ABL != 2) {
      if (t + 3 < NT) stage((t + 3) & 63, (t + 3) & 3);
    }
    if constexpr (ABL != 1) compute(t & 3);
  }

  if constexpr (ABL == 2) {
    // keep the whole compute chain live without storing (rule 17)
#pragma unroll
    for (int g = 0; g < 2; g++) {
      asm volatile("" :: "v"(lpacc[g][0]), "v"(lpacc[g][1]), "v"(lpacc[g][2]), "v"(lpacc[g][3]));
#pragma unroll
      for (int dt = 0; dt < 4; dt++)
        asm volatile("" :: "v"(O[g][dt][0]), "v"(O[g][dt][1]), "v"(O[g][dt][2]), "v"(O[g][dt][3]));
    }
    return;
  }

  if constexpr (ABL == 0) {
#pragma unroll
    for (int g = 0; g < 2; g++) {
      float rl = __builtin_amdgcn_rcpf(lpacc[g][0]);
      int q = q0 + g * 16 + l15;
      long colq = q & 511;
      long rowbase = (long)b * 1024 + (long)h * 128 + (q >> 9);
#pragma unroll
      for (int dt = 0; dt < 4; dt++) {
#pragma unroll
        for (int r = 0; r < 4; r++) {
          int dv = dt * 16 + quad * 4 + r;
          float val = O[g][dt][r] * rl;
          float hs = val * fminf(fmaxf(val + 3.f, 0.f), 6.f) * (1.f / 6.f);
          outp[(rowbase + (long)dv * 2) * 512 + colq] = (bf16_t)hs;
        }
      }
    }
  }
}

extern "C" void kernel_launch(void* const* d_in, const int* in_sizes, int n_in,
                              void* d_out, int out_size, void* d_ws, size_t ws_size,
                              hipStream_t stream)
{
  const float* x    = (const float*)d_in[0];
  const float* Wkv  = (const float*)d_in[1];
  const float* bkv  = (const float*)d_in[2];
  const float* g_kv = (const float*)d_in[3];
  const float* b_kv = (const float*)d_in[4];
  const float* m_kv = (const float*)d_in[5];
  const float* v_kv = (const float*)d_in[6];
  const float* Wq   = (const float*)d_in[7];
  const float* bq   = (const float*)d_in[8];
  const float* g_q  = (const float*)d_in[9];
  const float* b_q  = (const float*)d_in[10];
  const float* m_q  = (const float*)d_in[11];
  const float* v_q  = (const float*)d_in[12];
  const float* Wp   = (const float*)d_in[13];
  const float* bp   = (const float*)d_in[14];
  const float* g_p  = (const float*)d_in[15];
  const float* b_p  = (const float*)d_in[16];
  const float* m_p  = (const float*)d_in[17];
  const float* v_p  = (const float*)d_in[18];

  char* ws = (char*)d_ws;
  bf16_t* xb   = (bf16_t*)ws; ws += (long)8 * 4096 * 256 * 2;
  bf16_t* WkT  = (bf16_t*)ws; ws += (long)128 * 256 * 2;   // | contiguous: Wf[768][256]
  bf16_t* WvT  = (bf16_t*)ws; ws += (long)512 * 256 * 2;   // |
  bf16_t* Wq_t = (bf16_t*)ws; ws += (long)128 * 256 * 2;   // |
  bf16_t* Wp_t = (bf16_t*)ws; ws += (long)512 * 512 * 2;
  bf16_t* Qbuf = (bf16_t*)ws; ws += (long)64 * 1024 * 16 * 2;
  bf16_t* Kbuf = (bf16_t*)ws; ws += (long)64 * 4096 * 16 * 2;
  bf16_t* Vtb  = (bf16_t*)ws; ws += (long)64 * 64 * 4096 * 2;
  bf16_t* outp = (bf16_t*)ws; ws += (long)8192 * 512 * 2;
  bf16_t* scr  = (bf16_t*)ws; ws += (long)8192 * 512 * 2;   // diagnostic sink (never read)
  ws += 16384;  // slack

  // cvt + all weight transposes in one launch
  prep<<<dim3(4544), 256, 0, stream>>>(x, xb, Wkv, WkT, WvT, Wq, Wq_t, Wp, Wp_t);

  // fused K/V/Q projection
  qkv_fused<<<dim3(1536), 512, 0, stream>>>(xb, WkT,
      bkv, g_kv, b_kv, m_kv, v_kv, bq, g_q, b_q, m_q, v_q,
      Kbuf, Vtb, Qbuf);

  // real attention (exact R8 config)
  attn_abl<0><<<dim3(512), 256, 0, stream>>>(Qbuf, Kbuf, Vtb, outp);

  // fused output projection
  proj_fused<<<dim3(256), 512, 0, stream>>>(outp, Wp_t, bp, g_p, b_p, m_p, v_p, (float*)d_out);

  // ---- diagnostics (timing only; write nothing) ----
  attn_abl<1><<<dim3(512), 256, 0, stream>>>(Qbuf, Kbuf, Vtb, scr);  // stage-only, 4x tiles
  attn_abl<2><<<dim3(512), 256, 0, stream>>>(Qbuf, Kbuf, Vtb, scr);  // compute-only, 4x tiles
}

// Round 11
// 205.692 us; speedup vs baseline: 2.0741x; 2.0741x over previous
//
#include <hip/hip_runtime.h>

typedef __bf16 bf16_t;
typedef __bf16 bf16x4 __attribute__((ext_vector_type(4)));
typedef __bf16 bf16x8 __attribute__((ext_vector_type(8)));
typedef short s16x4 __attribute__((ext_vector_type(4)));
typedef float f32x4 __attribute__((ext_vector_type(4)));

#define BN_EPS 1e-3f

#define GLOAD_LDS16(g, l) \
  __builtin_amdgcn_global_load_lds((const __attribute__((address_space(1))) void*)(g), \
                                   (__attribute__((address_space(3))) void*)(l), 16, 0, 0)

// =============== prep: cvt + all 3 weight transposes in ONE launch ===============
// (R8, unchanged)
__global__ __launch_bounds__(256) void prep(
    const float* __restrict__ x, bf16_t* __restrict__ xb,
    const float* __restrict__ Wkv, bf16_t* __restrict__ outK, bf16_t* __restrict__ outV,
    const float* __restrict__ Wq, bf16_t* __restrict__ Wq_t,
    const float* __restrict__ Wp, bf16_t* __restrict__ Wp_t)
{
  __shared__ bf16_t t[32][33];
  const int id = blockIdx.x;
  if (id < 4096) {
    long i = ((long)id * 256 + threadIdx.x) * 8;
    f32x4 a = *(const f32x4*)(x + i);
    f32x4 b = *(const f32x4*)(x + i + 4);
    bf16x8 o;
    o[0] = (bf16_t)a[0]; o[1] = (bf16_t)a[1]; o[2] = (bf16_t)a[2]; o[3] = (bf16_t)a[3];
    o[4] = (bf16_t)b[0]; o[5] = (bf16_t)b[1]; o[6] = (bf16_t)b[2]; o[7] = (bf16_t)b[3];
    *(bf16x8*)(xb + i) = o;
    return;
  }
  const int tx = threadIdx.x & 31, ty = threadIdx.x >> 5;
  if (id < 4256) {                       // Wkv split-transpose [256][640]
    int id2 = id - 4096;
    int bx = (id2 % 20) * 32, by = (id2 / 20) * 32;
#pragma unroll
    for (int i = 0; i < 32; i += 8)
      t[ty + i][tx] = (bf16_t)Wkv[(long)(by + ty + i) * 640 + (bx + tx)];
    __syncthreads();
#pragma unroll
    for (int i = 0; i < 32; i += 8) {
      int c = bx + ty + i;
      int h = c / 80, r80 = c - h * 80;
      bf16_t v = t[tx][ty + i];
      if (r80 < 16)
        outK[(long)(h * 16 + r80) * 256 + (by + tx)] = v;
      else
        outV[(long)(h * 64 + (r80 - 16)) * 256 + (by + tx)] = v;
    }
  } else if (id < 4288) {                // Wq transpose: fp32 [256][128] -> [128][256]
    int id3 = id - 4256;
    int bx = (id3 & 3) * 32, by = (id3 >> 2) * 32;
#pragma unroll
    for (int i = 0; i < 32; i += 8)
      t[ty + i][tx] = (bf16_t)Wq[(long)(by + ty + i) * 128 + (bx + tx)];
    __syncthreads();
#pragma unroll
    for (int i = 0; i < 32; i += 8)
      Wq_t[(long)(bx + ty + i) * 256 + (by + tx)] = t[tx][ty + i];
  } else {                               // Wp transpose: fp32 [512][512] -> [512][512]
    int id4 = id - 4288;
    int bx = (id4 & 15) * 32, by = (id4 >> 4) * 32;
#pragma unroll
    for (int i = 0; i < 32; i += 8)
      t[ty + i][tx] = (bf16_t)Wp[(long)(by + ty + i) * 512 + (bx + tx)];
    __syncthreads();
#pragma unroll
    for (int i = 0; i < 32; i += 8)
      Wp_t[(long)(bx + ty + i) * 512 + (by + tx)] = t[tx][ty + i];
  }
}

// =============== fused QKV projection GEMM: x[32768,256] @ Wf[768,256]^T ===============
// (R6, unchanged)
__global__ __launch_bounds__(512, 1) void qkv_fused(
    const bf16_t* __restrict__ xb, const bf16_t* __restrict__ Wf,
    const float* __restrict__ bkv, const float* __restrict__ g_kv,
    const float* __restrict__ b_kv, const float* __restrict__ m_kv,
    const float* __restrict__ v_kv,
    const float* __restrict__ bq, const float* __restrict__ g_q,
    const float* __restrict__ b_q, const float* __restrict__ m_q,
    const float* __restrict__ v_q,
    bf16_t* __restrict__ Kbuf, bf16_t* __restrict__ Vtb, bf16_t* __restrict__ Qbuf)
{
  __shared__ __align__(16) char Xs[65536];   // [128 rows][256 k] bf16, swizzled units
  __shared__ __align__(16) char Ws[65536];   // [128 rows][256 k] bf16, swizzled units

  const int tid = threadIdx.x;
  const int lane = tid & 63, w = tid >> 6;        // 8 waves
  const int quad = lane >> 4, l15 = lane & 15;
  const int wm = w >> 2, wn = w & 3;              // wave grid 2x4

  const int id = blockIdx.x;
  const int xcd = id & 7, slot = id >> 3;         // slot 0..191
  const int sd6 = slot / 6;
  const int mt = xcd * 32 + sd6;                  // 0..255 (contiguous per XCD)
  const int nt = slot - sd6 * 6;                  // 0..5
  const int blockM = mt * 128, blockN = nt * 128;

  {
    const int r_lo = w * 2 + (lane >> 5);                 // row within 16-row round
    const int soff = ((lane & 31) ^ (r_lo & 7)) << 4;     // swizzled source byte in row
#pragma unroll
    for (int rnd = 0; rnd < 8; rnd++) {
      const int row = rnd * 16 + r_lo;
      GLOAD_LDS16((const char*)xb + (long)(blockM + row) * 512 + soff,
                  &Xs[rnd * 8192 + w * 1024]);
      GLOAD_LDS16((const char*)Wf + (long)(blockN + row) * 512 + soff,
                  &Ws[rnd * 8192 + w * 1024]);
    }
  }
  __syncthreads();

  const int sw = l15 & 7;
  f32x4 acc[4][2] = {};
#pragma unroll
  for (int ks = 0; ks < 8; ks++) {
    const int u = ks * 4 + quad;
    const int su = (u ^ sw) << 4;
    bf16x8 af[4];
#pragma unroll
    for (int mi = 0; mi < 4; mi++)
      af[mi] = *(const bf16x8*)(&Xs[(wm * 64 + mi * 16 + l15) * 512 + su]);
    bf16x8 bf_[2];
#pragma unroll
    for (int ni = 0; ni < 2; ni++)
      bf_[ni] = *(const bf16x8*)(&Ws[(wn * 32 + ni * 16 + l15) * 512 + su]);
#pragma unroll
    for (int mi = 0; mi < 4; mi++)
#pragma unroll
      for (int ni = 0; ni < 2; ni++)
        acc[mi][ni] = __builtin_amdgcn_mfma_f32_16x16x32_bf16(af[mi], bf_[ni], acc[mi][ni], 0, 0, 0);
  }

#pragma unroll
  for (int ni = 0; ni < 2; ni++) {
    const int nfbase = blockN + wn * 32 + ni * 16;
    const int col = nfbase + l15;
    float s, t, bia;
    if (nfbase < 128) {            // K channels
      int cp = (col >> 4) * 80 + (col & 15);
      s = g_kv[cp] / sqrtf(v_kv[cp] + BN_EPS);
      t = b_kv[cp] - m_kv[cp] * s;
      bia = bkv[cp];
      int h = col >> 4, d = col & 15;
#pragma unroll
      for (int mi = 0; mi < 4; mi++)
#pragma unroll
        for (int r = 0; r < 4; r++) {
          int grow = blockM + wm * 64 + mi * 16 + quad * 4 + r;
          int b = grow >> 12, seq = grow & 4095;
          float y = (acc[mi][ni][r] + bia) * s + t;
          Kbuf[((long)((b * 8 + h) * 4096 + seq)) * 16 + d] = (bf16_t)y;
        }
    } else if (nfbase < 640) {     // V channels -> interleaved Vt
      int ch = col - 128;
      int cp = (ch >> 6) * 80 + 16 + (ch & 63);
      s = g_kv[cp] / sqrtf(v_kv[cp] + BN_EPS);
      t = b_kv[cp] - m_kv[cp] * s;
      bia = bkv[cp];
      int h2 = ch >> 6, dv = ch & 63;
#pragma unroll
      for (int mi = 0; mi < 4; mi++)
#pragma unroll
        for (int r = 0; r < 4; r++) {
          int grow = blockM + wm * 64 + mi * 16 + quad * 4 + r;
          int b = grow >> 12, seq = grow & 4095;
          int kb = seq >> 5, s32 = seq & 31;
          int qd = (s32 & 15) >> 2, j = (s32 >> 4) * 4 + (s32 & 3);
          float y = (acc[mi][ni][r] + bia) * s + t;
          Vtb[(((long)(b * 8 + h2)) << 18) + (kb << 11) + (qd << 9) + (dv << 3) + j] = (bf16_t)y;
        }
    } else {                        // Q channels (strided-subsampled rows only)
      int qc = col - 640;
      s = g_q[qc] / sqrtf(v_q[qc] + BN_EPS);
      t = b_q[qc] - m_q[qc] * s;
      bia = bq[qc];
      int h = qc >> 4, d = qc & 15;
#pragma unroll
      for (int mi = 0; mi < 4; mi++) {
        if ((((blockM + wm * 64 + mi * 16) >> 6) & 1) != 0) continue;
#pragma unroll
        for (int r = 0; r < 4; r += 2) {
          int grow = blockM + wm * 64 + mi * 16 + quad * 4 + r;
          int b = grow >> 12, seq = grow & 4095;
          int qp = ((seq >> 7) << 5) + ((seq & 63) >> 1);
          float y = (acc[mi][ni][r] + bia) * s + t;
          Qbuf[((long)((b * 8 + h) * 1024 + qp)) * 16 + d] = (bf16_t)(y * 0.36067376f);
        }
      }
    }
  }
}

// =============== fused output projection: outp[8192,512] @ WpT[512,512]^T + BN ===============
// (R7, unchanged)
__global__ __launch_bounds__(512, 1) void proj_fused(
    const bf16_t* __restrict__ A, const bf16_t* __restrict__ Wt,
    const float* __restrict__ bias, const float* __restrict__ gamma,
    const float* __restrict__ beta, const float* __restrict__ mean,
    const float* __restrict__ var, float* __restrict__ outf)
{
  __shared__ __align__(16) char Xs[65536];
  __shared__ __align__(16) char Wl[65536];

  const int tid = threadIdx.x;
  const int lane = tid & 63, w = tid >> 6;
  const int quad = lane >> 4, l15 = lane & 15;
  const int wm = w >> 2, wn = w & 3;

  const int id = blockIdx.x;
  const int xcd = id & 7, slot = id >> 3;
  const int mt = xcd * 8 + (slot >> 2);
  const int nt = slot & 3;
  const int blockM = mt * 128, blockN = nt * 128;

  const int r_lo = w * 2 + (lane >> 5);
  const int soff = ((lane & 31) ^ (r_lo & 7)) << 4;
  const int sw = l15 & 7;
  f32x4 acc[4][2] = {};

#pragma unroll
  for (int kc = 0; kc < 2; kc++) {
    if (kc) __syncthreads();
#pragma unroll
    for (int rnd = 0; rnd < 8; rnd++) {
      const int row = rnd * 16 + r_lo;
      GLOAD_LDS16((const char*)A  + (long)(blockM + row) * 1024 + kc * 512 + soff,
                  &Xs[rnd * 8192 + w * 1024]);
      GLOAD_LDS16((const char*)Wt + (long)(blockN + row) * 1024 + kc * 512 + soff,
                  &Wl[rnd * 8192 + w * 1024]);
    }
    __syncthreads();

#pragma unroll
    for (int ks = 0; ks < 8; ks++) {
      const int u = ks * 4 + quad;
      const int su = (u ^ sw) << 4;
      bf16x8 af[4];
#pragma unroll
      for (int mi = 0; mi < 4; mi++)
        af[mi] = *(const bf16x8*)(&Xs[(wm * 64 + mi * 16 + l15) * 512 + su]);
      bf16x8 bw[2];
#pragma unroll
      for (int ni = 0; ni < 2; ni++)
        bw[ni] = *(const bf16x8*)(&Wl[(wn * 32 + ni * 16 + l15) * 512 + su]);
#pragma unroll
      for (int mi = 0; mi < 4; mi++)
#pragma unroll
        for (int ni = 0; ni < 2; ni++)
          acc[mi][ni] = __builtin_amdgcn_mfma_f32_16x16x32_bf16(af[mi], bw[ni], acc[mi][ni], 0, 0, 0);
    }
  }

#pragma unroll
  for (int ni = 0; ni < 2; ni++) {
    int col = blockN + wn * 32 + ni * 16 + l15;
    float s = gamma[col] / sqrtf(var[col] + BN_EPS);
    float t = beta[col] - mean[col] * s;
    float bia = bias[col];
#pragma unroll
    for (int mi = 0; mi < 4; mi++)
#pragma unroll
      for (int r = 0; r < 4; r++) {
        int grow = blockM + wm * 64 + mi * 16 + quad * 4 + r;
        float y = (acc[mi][ni][r] + bia) * s + t;
        outf[(long)grow * 512 + col] = y;
      }
  }
}

// ---------------- flash attention: R8 config + cross-tile compute pipelining ----------------
// R11. Ablation (R10) partitioned the 66 us wall: compute-only = 51.4 us/unit (78%),
// stage-only = ~3, interaction ~12. Even compute-only is ~40% dep-chain stall (52% VALU /
// 14% true-MFMA cycles). Root cause of the R6/R7/R8 66-us invariance: sched_barrier(0)
// after every s_barrier FULLY pins the schedule -- the compiler cannot software-pipeline
// the ds_read->QK->exp->pack->PV chain across tiles, so wave-count/LDS-traffic changes
// couldn't matter. Fix: sched_barrier(0x40F) = ALU|VALU|SALU|MFMA|TRANS may cross the
// barrier; ALL memory ops (VMEM 0x10/20/40, DS 0x80/100/200) stay pinned. Correctness:
// staging can't hoist above the barrier (VMEM pinned) -> no buffer race; next-tile ds_reads
// can't hoist (DS pinned) -> no stale reads; tile-t's exp/PV sinking below barrier t+1 is
// register-only and ordered by accumulator dependencies. Everything else = R8 (66 us best).
// PRE-COMMIT: if attn >= 64 us, attn is at its structural plateau; pivot to qkv/proj or stop.
__global__ __launch_bounds__(256, 2) void attn_kernel(
    const bf16_t* __restrict__ Q, const bf16_t* __restrict__ K,
    const bf16_t* __restrict__ Vt, bf16_t* __restrict__ outp)
{
  const int tid = threadIdx.x;
  const int lane = tid & 63, w = tid >> 6;                // 4 waves
  const int quad = lane >> 4, l15 = lane & 15;
  const int bh = blockIdx.x & 63, qb = blockIdx.x >> 6;   // qb 0..7
  const int b = bh >> 3, h = bh & 7;
  const bf16_t* Qp = Q + (long)bh * 1024 * 16;
  const char* Kg = (const char*)(K + (long)bh * 4096 * 16);     // [key][16d], 32 B/row
  const char* Vg = (const char*)(Vt + ((long)bh << 18));        // interleaved, 512 KB/bh

  __shared__ __align__(16) char Kl[4][2048];
  __shared__ __align__(16) char Vl[4][8192];

  const int q0 = qb * 128 + w * 32;
  bf16x8 qB8[2];
#pragma unroll
  for (int g = 0; g < 2; g++) {
    bf16x8 qv = *(const bf16x8*)(Qp + (long)(q0 + g * 16 + l15) * 16 + (quad & 1) * 8);
    bf16x8 zq = {};
    qB8[g] = (quad < 2) ? qv : zq;
  }

  f32x4 O[2][4] = {};        // [qgroup][dv tile]: lane holds (q=l15, dv=dt*16+quad*4+r)
  f32x4 lpacc[2] = {};       // ones-MFMA: every row = sum_k P[k][q=l15]
  const f32x4 zf = {0.f, 0.f, 0.f, 0.f};

  bf16x8 ones8;
#pragma unroll
  for (int i = 0; i < 8; i++) ones8[i] = (bf16_t)1.f;

  const char* vsrc = Vg + (long)lane * 16;
  const char* ksrc = Kg + (long)lane * 32 + (w - 2) * 16;

  auto stage = [&](int t, int buf) {
    if (w < 2) {
#pragma unroll
      for (int c = 0; c < 2; c++)
        GLOAD_LDS16(vsrc + (long)t * 8192 + (w * 2 + c) * 1024, &Vl[buf][(w * 2 + c) * 1024]);
    } else {
#pragma unroll
      for (int c = 0; c < 2; c++)
        GLOAD_LDS16(vsrc + (long)t * 8192 + ((w - 2) * 2 + 4 + c) * 1024,
                    &Vl[buf][((w - 2) * 2 + 4 + c) * 1024]);
      GLOAD_LDS16(ksrc + (long)t * 2048, &Kl[buf][(w - 2) * 1024]);
    }
  };

  const int krow_off = (quad & 1) * 1024;

  auto compute = [&](int buf) {
#pragma unroll
    for (int kh = 0; kh < 2; kh++) {
      bf16x8 k0 = *(const bf16x8*)(&Kl[buf][krow_off + (kh * 32 + l15) * 16]);
      bf16x8 k1 = *(const bf16x8*)(&Kl[buf][krow_off + (kh * 32 + 16 + l15) * 16]);
      bf16x8 vA[4];
#pragma unroll
      for (int dt = 0; dt < 4; dt++)
        vA[dt] = *(const bf16x8*)(&Vl[buf][kh * 4096 + quad * 1024 + (dt * 16 + l15) * 16]);
#pragma unroll
      for (int g = 0; g < 2; g++) {
        f32x4 S0 = __builtin_amdgcn_mfma_f32_16x16x32_bf16(k0, qB8[g], zf, 0, 0, 0);
        f32x4 S1 = __builtin_amdgcn_mfma_f32_16x16x32_bf16(k1, qB8[g], zf, 0, 0, 0);
        bf16x8 pb;
        pb[0] = (bf16_t)__builtin_amdgcn_exp2f(S0[0]);
        pb[1] = (bf16_t)__builtin_amdgcn_exp2f(S0[1]);
        pb[2] = (bf16_t)__builtin_amdgcn_exp2f(S0[2]);
        pb[3] = (bf16_t)__builtin_amdgcn_exp2f(S0[3]);
        pb[4] = (bf16_t)__builtin_amdgcn_exp2f(S1[0]);
        pb[5] = (bf16_t)__builtin_amdgcn_exp2f(S1[1]);
        pb[6] = (bf16_t)__builtin_amdgcn_exp2f(S1[2]);
        pb[7] = (bf16_t)__builtin_amdgcn_exp2f(S1[3]);
        lpacc[g] = __builtin_amdgcn_mfma_f32_16x16x32_bf16(ones8, pb, lpacc[g], 0, 0, 0);
#pragma unroll
        for (int dt = 0; dt < 4; dt++)
          O[g][dt] = __builtin_amdgcn_mfma_f32_16x16x32_bf16(vA[dt], pb, O[g][dt], 0, 0, 0);
      }
    }
  };

  stage(0, 0);
  stage(1, 1);
  stage(2, 2);
#pragma unroll 4
  for (int t = 0; t < 64; t++) {
    if (t + 2 < 64) {              // tiles t+1, t+2 may stay in flight
      if (w < 2) asm volatile("s_waitcnt vmcnt(4)" ::: "memory");
      else       asm volatile("s_waitcnt vmcnt(6)" ::: "memory");
    } else if (t + 1 < 64) {
      if (w < 2) asm volatile("s_waitcnt vmcnt(2)" ::: "memory");
      else       asm volatile("s_waitcnt vmcnt(3)" ::: "memory");
    } else {
      asm volatile("s_waitcnt vmcnt(0)" ::: "memory");
    }
    __builtin_amdgcn_s_barrier();
    // Allow compute (ALU|VALU|SALU|MFMA|TRANS = 0x40F) to pipeline ACROSS the barrier;
    // memory ops (VMEM, DS) remain pinned -> staging/ds_read ordering unchanged.
    __builtin_amdgcn_sched_barrier(0x40F);
    if (t + 3 < 64) stage(t + 3, (t + 3) & 3);   // buf (t-1)&3: freed by all waves pre-barrier
    compute(t & 3);
  }

#pragma unroll
  for (int g = 0; g < 2; g++) {
    float rl = __builtin_amdgcn_rcpf(lpacc[g][0]);
    int q = q0 + g * 16 + l15;
    long colq = q & 511;
    long rowbase = (long)b * 1024 + (long)h * 128 + (q >> 9);
#pragma unroll
    for (int dt = 0; dt < 4; dt++) {
#pragma unroll
      for (int r = 0; r < 4; r++) {
        int dv = dt * 16 + quad * 4 + r;
        float val = O[g][dt][r] * rl;
        float hs = val * fminf(fmaxf(val + 3.f, 0.f), 6.f) * (1.f / 6.f);
        outp[(rowbase + (long)dv * 2) * 512 + colq] = (bf16_t)hs;
      }
    }
  }
}

extern "C" void kernel_launch(void* const* d_in, const int* in_sizes, int n_in,
                              void* d_out, int out_size, void* d_ws, size_t ws_size,
                              hipStream_t stream)
{
  const float* x    = (const float*)d_in[0];
  const float* Wkv  = (const float*)d_in[1];
  const float* bkv  = (const float*)d_in[2];
  const float* g_kv = (const float*)d_in[3];
  const float* b_kv = (const float*)d_in[4];
  const float* m_kv = (const float*)d_in[5];
  const float* v_kv = (const float*)d_in[6];
  const float* Wq   = (const float*)d_in[7];
  const float* bq   = (const float*)d_in[8];
  const float* g_q  = (const float*)d_in[9];
  const float* b_q  = (const float*)d_in[10];
  const float* m_q  = (const float*)d_in[11];
  const float* v_q  = (const float*)d_in[12];
  const float* Wp   = (const float*)d_in[13];
  const float* bp   = (const float*)d_in[14];
  const float* g_p  = (const float*)d_in[15];
  const float* b_p  = (const float*)d_in[16];
  const float* m_p  = (const float*)d_in[17];
  const float* v_p  = (const float*)d_in[18];

  char* ws = (char*)d_ws;
  bf16_t* xb   = (bf16_t*)ws; ws += (long)8 * 4096 * 256 * 2;
  bf16_t* WkT  = (bf16_t*)ws; ws += (long)128 * 256 * 2;   // | contiguous: Wf[768][256]
  bf16_t* WvT  = (bf16_t*)ws; ws += (long)512 * 256 * 2;   // |
  bf16_t* Wq_t = (bf16_t*)ws; ws += (long)128 * 256 * 2;   // |
  bf16_t* Wp_t = (bf16_t*)ws; ws += (long)512 * 512 * 2;
  bf16_t* Qbuf = (bf16_t*)ws; ws += (long)64 * 1024 * 16 * 2;
  bf16_t* Kbuf = (bf16_t*)ws; ws += (long)64 * 4096 * 16 * 2;
  bf16_t* Vtb  = (bf16_t*)ws; ws += (long)64 * 64 * 4096 * 2;
  bf16_t* outp = (bf16_t*)ws; ws += (long)8192 * 512 * 2;
  ws += 16384;  // slack

  // cvt + all weight transposes in one launch
  prep<<<dim3(4544), 256, 0, stream>>>(x, xb, Wkv, WkT, WvT, Wq, Wq_t, Wp, Wp_t);

  // fused K/V/Q projection
  qkv_fused<<<dim3(1536), 512, 0, stream>>>(xb, WkT,
      bkv, g_kv, b_kv, m_kv, v_kv, bq, g_q, b_q, m_q, v_q,
      Kbuf, Vtb, Qbuf);

  attn_kernel<<<dim3(512), 256, 0, stream>>>(Qbuf, Kbuf, Vtb, outp);

  // fused output projection
  proj_fused<<<dim3(256), 512, 0, stream>>>(outp, Wp_t, bp, g_p, b_p, m_p, v_p, (float*)d_out);
}

// Round 12
// 201.139 us; speedup vs baseline: 2.1211x; 1.0226x over previous
//
#include <hip/hip_runtime.h>

typedef __bf16 bf16_t;
typedef __bf16 bf16x4 __attribute__((ext_vector_type(4)));
typedef __bf16 bf16x8 __attribute__((ext_vector_type(8)));
typedef short s16x4 __attribute__((ext_vector_type(4)));
typedef float f32x4 __attribute__((ext_vector_type(4)));

#define BN_EPS 1e-3f

#define GLOAD_LDS16(g, l) \
  __builtin_amdgcn_global_load_lds((const __attribute__((address_space(1))) void*)(g), \
                                   (__attribute__((address_space(3))) void*)(l), 16, 0, 0)

// =============== prep: cvt + all 3 weight transposes in ONE launch ===============
// (R8, unchanged)
__global__ __launch_bounds__(256) void prep(
    const float* __restrict__ x, bf16_t* __restrict__ xb,
    const float* __restrict__ Wkv, bf16_t* __restrict__ outK, bf16_t* __restrict__ outV,
    const float* __restrict__ Wq, bf16_t* __restrict__ Wq_t,
    const float* __restrict__ Wp, bf16_t* __restrict__ Wp_t)
{
  __shared__ bf16_t t[32][33];
  const int id = blockIdx.x;
  if (id < 4096) {
    long i = ((long)id * 256 + threadIdx.x) * 8;
    f32x4 a = *(const f32x4*)(x + i);
    f32x4 b = *(const f32x4*)(x + i + 4);
    bf16x8 o;
    o[0] = (bf16_t)a[0]; o[1] = (bf16_t)a[1]; o[2] = (bf16_t)a[2]; o[3] = (bf16_t)a[3];
    o[4] = (bf16_t)b[0]; o[5] = (bf16_t)b[1]; o[6] = (bf16_t)b[2]; o[7] = (bf16_t)b[3];
    *(bf16x8*)(xb + i) = o;
    return;
  }
  const int tx = threadIdx.x & 31, ty = threadIdx.x >> 5;
  if (id < 4256) {                       // Wkv split-transpose [256][640]
    int id2 = id - 4096;
    int bx = (id2 % 20) * 32, by = (id2 / 20) * 32;
#pragma unroll
    for (int i = 0; i < 32; i += 8)
      t[ty + i][tx] = (bf16_t)Wkv[(long)(by + ty + i) * 640 + (bx + tx)];
    __syncthreads();
#pragma unroll
    for (int i = 0; i < 32; i += 8) {
      int c = bx + ty + i;
      int h = c / 80, r80 = c - h * 80;
      bf16_t v = t[tx][ty + i];
      if (r80 < 16)
        outK[(long)(h * 16 + r80) * 256 + (by + tx)] = v;
      else
        outV[(long)(h * 64 + (r80 - 16)) * 256 + (by + tx)] = v;
    }
  } else if (id < 4288) {                // Wq transpose: fp32 [256][128] -> [128][256]
    int id3 = id - 4256;
    int bx = (id3 & 3) * 32, by = (id3 >> 2) * 32;
#pragma unroll
    for (int i = 0; i < 32; i += 8)
      t[ty + i][tx] = (bf16_t)Wq[(long)(by + ty + i) * 128 + (bx + tx)];
    __syncthreads();
#pragma unroll
    for (int i = 0; i < 32; i += 8)
      Wq_t[(long)(bx + ty + i) * 256 + (by + tx)] = t[tx][ty + i];
  } else {                               // Wp transpose: fp32 [512][512] -> [512][512]
    int id4 = id - 4288;
    int bx = (id4 & 15) * 32, by = (id4 >> 4) * 32;
#pragma unroll
    for (int i = 0; i < 32; i += 8)
      t[ty + i][tx] = (bf16_t)Wp[(long)(by + ty + i) * 512 + (bx + tx)];
    __syncthreads();
#pragma unroll
    for (int i = 0; i < 32; i += 8)
      Wp_t[(long)(bx + ty + i) * 512 + (by + tx)] = t[tx][ty + i];
  }
}

// =============== fused QKV projection GEMM: x[32768,256] @ Wf[768,256]^T ===============
// R12: K chunked 256 -> 2x128 so LDS halves to 64 KB (Xs 32K + Ws 32K) -> 2 blocks/CU.
// R6-R8 version was 1 block/CU single-shot: stage-128KB -> sync -> compute with NOTHING
// co-resident to hide the staging (same exposure R10's ablation quantified in attn).
// Now block B's compute/epilogue overlaps block A's staging; grid 1536 = 3 residency
// rounds instead of 6. Swizzle adapted to 16-unit (256 B) rows: read unit u^(l15&7),
// source pre-swizzled with row&7 (rnd*32 == 0 mod 8 -> row&7 = srow&7; involution).
// K-order kc0:ks0-3,kc1:ks0-3 == ks0-7 -> accumulation bit-identical. Epilogues unchanged.
__global__ __launch_bounds__(512, 4) void qkv_fused(
    const bf16_t* __restrict__ xb, const bf16_t* __restrict__ Wf,
    const float* __restrict__ bkv, const float* __restrict__ g_kv,
    const float* __restrict__ b_kv, const float* __restrict__ m_kv,
    const float* __restrict__ v_kv,
    const float* __restrict__ bq, const float* __restrict__ g_q,
    const float* __restrict__ b_q, const float* __restrict__ m_q,
    const float* __restrict__ v_q,
    bf16_t* __restrict__ Kbuf, bf16_t* __restrict__ Vtb, bf16_t* __restrict__ Qbuf)
{
  __shared__ __align__(16) char Xs[32768];   // [128 rows][128 k] bf16 chunk, swizzled units
  __shared__ __align__(16) char Ws[32768];

  const int tid = threadIdx.x;
  const int lane = tid & 63, w = tid >> 6;        // 8 waves
  const int quad = lane >> 4, l15 = lane & 15;
  const int wm = w >> 2, wn = w & 3;              // wave grid 2x4

  const int id = blockIdx.x;
  const int xcd = id & 7, slot = id >> 3;         // slot 0..191
  const int sd6 = slot / 6;
  const int mt = xcd * 32 + sd6;                  // 0..255 (contiguous per XCD)
  const int nt = slot - sd6 * 6;                  // 0..5
  const int blockM = mt * 128, blockN = nt * 128;

  // staging geometry: round = 32 rows x 256 B; wave w -> rows w*4+quad; unit = l15
  const int srow = w * 4 + quad;                        // row within round
  const int sunit = (l15 ^ (srow & 7)) << 4;            // pre-swizzled source byte

  const int sw = l15 & 7;
  f32x4 acc[4][2] = {};

#pragma unroll
  for (int kc = 0; kc < 2; kc++) {
    if (kc) __syncthreads();                      // all reads of chunk 0 done before overwrite
#pragma unroll
    for (int rnd = 0; rnd < 4; rnd++) {
      const int row = rnd * 32 + srow;
      GLOAD_LDS16((const char*)xb + (long)(blockM + row) * 512 + kc * 256 + sunit,
                  &Xs[rnd * 8192 + w * 1024]);
      GLOAD_LDS16((const char*)Wf + (long)(blockN + row) * 512 + kc * 256 + sunit,
                  &Ws[rnd * 8192 + w * 1024]);
    }
    __syncthreads();                              // drains DMA (vmcnt0) + fences LDS

#pragma unroll
    for (int ks = 0; ks < 4; ks++) {
      const int u = ks * 4 + quad;                // 16B unit within 256B chunk-row
      const int su = (u ^ sw) << 4;
      bf16x8 af[4];
#pragma unroll
      for (int mi = 0; mi < 4; mi++)
        af[mi] = *(const bf16x8*)(&Xs[(wm * 64 + mi * 16 + l15) * 256 + su]);
      bf16x8 bf_[2];
#pragma unroll
      for (int ni = 0; ni < 2; ni++)
        bf_[ni] = *(const bf16x8*)(&Ws[(wn * 32 + ni * 16 + l15) * 256 + su]);
#pragma unroll
      for (int mi = 0; mi < 4; mi++)
#pragma unroll
        for (int ni = 0; ni < 2; ni++)
          acc[mi][ni] = __builtin_amdgcn_mfma_f32_16x16x32_bf16(af[mi], bf_[ni], acc[mi][ni], 0, 0, 0);
    }
  }

  // ---- epilogue: per n-region BN + scatter (unchanged, verified R6) ----
#pragma unroll
  for (int ni = 0; ni < 2; ni++) {
    const int nfbase = blockN + wn * 32 + ni * 16;
    const int col = nfbase + l15;
    float s, t, bia;
    if (nfbase < 128) {            // K channels
      int cp = (col >> 4) * 80 + (col & 15);
      s = g_kv[cp] / sqrtf(v_kv[cp] + BN_EPS);
      t = b_kv[cp] - m_kv[cp] * s;
      bia = bkv[cp];
      int h = col >> 4, d = col & 15;
#pragma unroll
      for (int mi = 0; mi < 4; mi++)
#pragma unroll
        for (int r = 0; r < 4; r++) {
          int grow = blockM + wm * 64 + mi * 16 + quad * 4 + r;
          int b = grow >> 12, seq = grow & 4095;
          float y = (acc[mi][ni][r] + bia) * s + t;
          Kbuf[((long)((b * 8 + h) * 4096 + seq)) * 16 + d] = (bf16_t)y;
        }
    } else if (nfbase < 640) {     // V channels -> interleaved Vt
      int ch = col - 128;
      int cp = (ch >> 6) * 80 + 16 + (ch & 63);
      s = g_kv[cp] / sqrtf(v_kv[cp] + BN_EPS);
      t = b_kv[cp] - m_kv[cp] * s;
      bia = bkv[cp];
      int h2 = ch >> 6, dv = ch & 63;
#pragma unroll
      for (int mi = 0; mi < 4; mi++)
#pragma unroll
        for (int r = 0; r < 4; r++) {
          int grow = blockM + wm * 64 + mi * 16 + quad * 4 + r;
          int b = grow >> 12, seq = grow & 4095;
          int kb = seq >> 5, s32 = seq & 31;
          int qd = (s32 & 15) >> 2, j = (s32 >> 4) * 4 + (s32 & 3);
          float y = (acc[mi][ni][r] + bia) * s + t;
          Vtb[(((long)(b * 8 + h2)) << 18) + (kb << 11) + (qd << 9) + (dv << 3) + j] = (bf16_t)y;
        }
    } else {                        // Q channels (strided-subsampled rows only)
      int qc = col - 640;
      s = g_q[qc] / sqrtf(v_q[qc] + BN_EPS);
      t = b_q[qc] - m_q[qc] * s;
      bia = bq[qc];
      int h = qc >> 4, d = qc & 15;
#pragma unroll
      for (int mi = 0; mi < 4; mi++) {
        if ((((blockM + wm * 64 + mi * 16) >> 6) & 1) != 0) continue;
#pragma unroll
        for (int r = 0; r < 4; r += 2) {
          int grow = blockM + wm * 64 + mi * 16 + quad * 4 + r;
          int b = grow >> 12, seq = grow & 4095;
          int qp = ((seq >> 7) << 5) + ((seq & 63) >> 1);
          float y = (acc[mi][ni][r] + bia) * s + t;
          Qbuf[((long)((b * 8 + h) * 1024 + qp)) * 16 + d] = (bf16_t)(y * 0.36067376f);
        }
      }
    }
  }
}

// =============== fused output projection: outp[8192,512] @ WpT[512,512]^T + BN ===============
// (R7, unchanged)
__global__ __launch_bounds__(512, 1) void proj_fused(
    const bf16_t* __restrict__ A, const bf16_t* __restrict__ Wt,
    const float* __restrict__ bias, const float* __restrict__ gamma,
    const float* __restrict__ beta, const float* __restrict__ mean,
    const float* __restrict__ var, float* __restrict__ outf)
{
  __shared__ __align__(16) char Xs[65536];
  __shared__ __align__(16) char Wl[65536];

  const int tid = threadIdx.x;
  const int lane = tid & 63, w = tid >> 6;
  const int quad = lane >> 4, l15 = lane & 15;
  const int wm = w >> 2, wn = w & 3;

  const int id = blockIdx.x;
  const int xcd = id & 7, slot = id >> 3;
  const int mt = xcd * 8 + (slot >> 2);
  const int nt = slot & 3;
  const int blockM = mt * 128, blockN = nt * 128;

  const int r_lo = w * 2 + (lane >> 5);
  const int soff = ((lane & 31) ^ (r_lo & 7)) << 4;
  const int sw = l15 & 7;
  f32x4 acc[4][2] = {};

#pragma unroll
  for (int kc = 0; kc < 2; kc++) {
    if (kc) __syncthreads();
#pragma unroll
    for (int rnd = 0; rnd < 8; rnd++) {
      const int row = rnd * 16 + r_lo;
      GLOAD_LDS16((const char*)A  + (long)(blockM + row) * 1024 + kc * 512 + soff,
                  &Xs[rnd * 8192 + w * 1024]);
      GLOAD_LDS16((const char*)Wt + (long)(blockN + row) * 1024 + kc * 512 + soff,
                  &Wl[rnd * 8192 + w * 1024]);
    }
    __syncthreads();

#pragma unroll
    for (int ks = 0; ks < 8; ks++) {
      const int u = ks * 4 + quad;
      const int su = (u ^ sw) << 4;
      bf16x8 af[4];
#pragma unroll
      for (int mi = 0; mi < 4; mi++)
        af[mi] = *(const bf16x8*)(&Xs[(wm * 64 + mi * 16 + l15) * 512 + su]);
      bf16x8 bw[2];
#pragma unroll
      for (int ni = 0; ni < 2; ni++)
        bw[ni] = *(const bf16x8*)(&Wl[(wn * 32 + ni * 16 + l15) * 512 + su]);
#pragma unroll
      for (int mi = 0; mi < 4; mi++)
#pragma unroll
        for (int ni = 0; ni < 2; ni++)
          acc[mi][ni] = __builtin_amdgcn_mfma_f32_16x16x32_bf16(af[mi], bw[ni], acc[mi][ni], 0, 0, 0);
    }
  }

#pragma unroll
  for (int ni = 0; ni < 2; ni++) {
    int col = blockN + wn * 32 + ni * 16 + l15;
    float s = gamma[col] / sqrtf(var[col] + BN_EPS);
    float t = beta[col] - mean[col] * s;
    float bia = bias[col];
#pragma unroll
    for (int mi = 0; mi < 4; mi++)
#pragma unroll
      for (int r = 0; r < 4; r++) {
        int grow = blockM + wm * 64 + mi * 16 + quad * 4 + r;
        float y = (acc[mi][ni][r] + bia) * s + t;
        outf[(long)grow * 512 + col] = y;
      }
  }
}

// ---------------- flash attention: EXACT R8 config (66 us best) ----------------
// R12: revert of R11's sched_barrier(0x40F) (regressed 66->72.5, VGPR 52->60: compute
// sinking across barriers extended accumulator live ranges; with runtime buf index the
// compiler can't rotate the chain anyway). R9-R11 established this schedule family's
// plateau at 66 us (compute-chain bound per R10 ablation: compute-only 51.4, stage 3,
// interaction 12). No further attn hypotheses; structural ceiling documented in-line.
__global__ __launch_bounds__(256, 2) void attn_kernel(
    const bf16_t* __restrict__ Q, const bf16_t* __restrict__ K,
    const bf16_t* __restrict__ Vt, bf16_t* __restrict__ outp)
{
  const int tid = threadIdx.x;
  const int lane = tid & 63, w = tid >> 6;                // 4 waves
  const int quad = lane >> 4, l15 = lane & 15;
  const int bh = blockIdx.x & 63, qb = blockIdx.x >> 6;   // qb 0..7
  const int b = bh >> 3, h = bh & 7;
  const bf16_t* Qp = Q + (long)bh * 1024 * 16;
  const char* Kg = (const char*)(K + (long)bh * 4096 * 16);     // [key][16d], 32 B/row
  const char* Vg = (const char*)(Vt + ((long)bh << 18));        // interleaved, 512 KB/bh

  __shared__ __align__(16) char Kl[4][2048];
  __shared__ __align__(16) char Vl[4][8192];

  const int q0 = qb * 128 + w * 32;
  bf16x8 qB8[2];
#pragma unroll
  for (int g = 0; g < 2; g++) {
    bf16x8 qv = *(const bf16x8*)(Qp + (long)(q0 + g * 16 + l15) * 16 + (quad & 1) * 8);
    bf16x8 zq = {};
    qB8[g] = (quad < 2) ? qv : zq;
  }

  f32x4 O[2][4] = {};        // [qgroup][dv tile]: lane holds (q=l15, dv=dt*16+quad*4+r)
  f32x4 lpacc[2] = {};       // ones-MFMA: every row = sum_k P[k][q=l15]
  const f32x4 zf = {0.f, 0.f, 0.f, 0.f};

  bf16x8 ones8;
#pragma unroll
  for (int i = 0; i < 8; i++) ones8[i] = (bf16_t)1.f;

  const char* vsrc = Vg + (long)lane * 16;
  const char* ksrc = Kg + (long)lane * 32 + (w - 2) * 16;

  auto stage = [&](int t, int buf) {
    if (w < 2) {
#pragma unroll
      for (int c = 0; c < 2; c++)
        GLOAD_LDS16(vsrc + (long)t * 8192 + (w * 2 + c) * 1024, &Vl[buf][(w * 2 + c) * 1024]);
    } else {
#pragma unroll
      for (int c = 0; c < 2; c++)
        GLOAD_LDS16(vsrc + (long)t * 8192 + ((w - 2) * 2 + 4 + c) * 1024,
                    &Vl[buf][((w - 2) * 2 + 4 + c) * 1024]);
      GLOAD_LDS16(ksrc + (long)t * 2048, &Kl[buf][(w - 2) * 1024]);
    }
  };

  const int krow_off = (quad & 1) * 1024;

  auto compute = [&](int buf) {
#pragma unroll
    for (int kh = 0; kh < 2; kh++) {
      bf16x8 k0 = *(const bf16x8*)(&Kl[buf][krow_off + (kh * 32 + l15) * 16]);
      bf16x8 k1 = *(const bf16x8*)(&Kl[buf][krow_off + (kh * 32 + 16 + l15) * 16]);
      bf16x8 vA[4];
#pragma unroll
      for (int dt = 0; dt < 4; dt++)
        vA[dt] = *(const bf16x8*)(&Vl[buf][kh * 4096 + quad * 1024 + (dt * 16 + l15) * 16]);
#pragma unroll
      for (int g = 0; g < 2; g++) {
        f32x4 S0 = __builtin_amdgcn_mfma_f32_16x16x32_bf16(k0, qB8[g], zf, 0, 0, 0);
        f32x4 S1 = __builtin_amdgcn_mfma_f32_16x16x32_bf16(k1, qB8[g], zf, 0, 0, 0);
        bf16x8 pb;
        pb[0] = (bf16_t)__builtin_amdgcn_exp2f(S0[0]);
        pb[1] = (bf16_t)__builtin_amdgcn_exp2f(S0[1]);
        pb[2] = (bf16_t)__builtin_amdgcn_exp2f(S0[2]);
        pb[3] = (bf16_t)__builtin_amdgcn_exp2f(S0[3]);
        pb[4] = (bf16_t)__builtin_amdgcn_exp2f(S1[0]);
        pb[5] = (bf16_t)__builtin_amdgcn_exp2f(S1[1]);
        pb[6] = (bf16_t)__builtin_amdgcn_exp2f(S1[2]);
        pb[7] = (bf16_t)__builtin_amdgcn_exp2f(S1[3]);
        lpacc[g] = __builtin_amdgcn_mfma_f32_16x16x32_bf16(ones8, pb, lpacc[g], 0, 0, 0);
#pragma unroll
        for (int dt = 0; dt < 4; dt++)
          O[g][dt] = __builtin_amdgcn_mfma_f32_16x16x32_bf16(vA[dt], pb, O[g][dt], 0, 0, 0);
      }
    }
  };

  stage(0, 0);
  stage(1, 1);
  stage(2, 2);
#pragma unroll 4
  for (int t = 0; t < 64; t++) {
    if (t + 2 < 64) {              // tiles t+1, t+2 may stay in flight
      if (w < 2) asm volatile("s_waitcnt vmcnt(4)" ::: "memory");
      else       asm volatile("s_waitcnt vmcnt(6)" ::: "memory");
    } else if (t + 1 < 64) {
      if (w < 2) asm volatile("s_waitcnt vmcnt(2)" ::: "memory");
      else       asm volatile("s_waitcnt vmcnt(3)" ::: "memory");
    } else {
      asm volatile("s_waitcnt vmcnt(0)" ::: "memory");
    }
    __builtin_amdgcn_s_barrier();
    __builtin_amdgcn_sched_barrier(0);
    if (t + 3 < 64) stage(t + 3, (t + 3) & 3);   // buf (t-1)&3: freed by all waves pre-barrier
    compute(t & 3);
  }

#pragma unroll
  for (int g = 0; g < 2; g++) {
    float rl = __builtin_amdgcn_rcpf(lpacc[g][0]);
    int q = q0 + g * 16 + l15;
    long colq = q & 511;
    long rowbase = (long)b * 1024 + (long)h * 128 + (q >> 9);
#pragma unroll
    for (int dt = 0; dt < 4; dt++) {
#pragma unroll
      for (int r = 0; r < 4; r++) {
        int dv = dt * 16 + quad * 4 + r;
        float val = O[g][dt][r] * rl;
        float hs = val * fminf(fmaxf(val + 3.f, 0.f), 6.f) * (1.f / 6.f);
        outp[(rowbase + (long)dv * 2) * 512 + colq] = (bf16_t)hs;
      }
    }
  }
}

extern "C" void kernel_launch(void* const* d_in, const int* in_sizes, int n_in,
                              void* d_out, int out_size, void* d_ws, size_t ws_size,
                              hipStream_t stream)
{
  const float* x    = (const float*)d_in[0];
  const float* Wkv  = (const float*)d_in[1];
  const float* bkv  = (const float*)d_in[2];
  const float* g_kv = (const float*)d_in[3];
  const float* b_kv = (const float*)d_in[4];
  const float* m_kv = (const float*)d_in[5];
  const float* v_kv = (const float*)d_in[6];
  const float* Wq   = (const float*)d_in[7];
  const float* bq   = (const float*)d_in[8];
  const float* g_q  = (const float*)d_in[9];
  const float* b_q  = (const float*)d_in[10];
  const float* m_q  = (const float*)d_in[11];
  const float* v_q  = (const float*)d_in[12];
  const float* Wp   = (const float*)d_in[13];
  const float* bp   = (const float*)d_in[14];
  const float* g_p  = (const float*)d_in[15];
  const float* b_p  = (const float*)d_in[16];
  const float* m_p  = (const float*)d_in[17];
  const float* v_p  = (const float*)d_in[18];

  char* ws = (char*)d_ws;
  bf16_t* xb   = (bf16_t*)ws; ws += (long)8 * 4096 * 256 * 2;
  bf16_t* WkT  = (bf16_t*)ws; ws += (long)128 * 256 * 2;   // | contiguous: Wf[768][256]
  bf16_t* WvT  = (bf16_t*)ws; ws += (long)512 * 256 * 2;   // |
  bf16_t* Wq_t = (bf16_t*)ws; ws += (long)128 * 256 * 2;   // |
  bf16_t* Wp_t = (bf16_t*)ws; ws += (long)512 * 512 * 2;
  bf16_t* Qbuf = (bf16_t*)ws; ws += (long)64 * 1024 * 16 * 2;
  bf16_t* Kbuf = (bf16_t*)ws; ws += (long)64 * 4096 * 16 * 2;
  bf16_t* Vtb  = (bf16_t*)ws; ws += (long)64 * 64 * 4096 * 2;
  bf16_t* outp = (bf16_t*)ws; ws += (long)8192 * 512 * 2;
  ws += 16384;  // slack

  // cvt + all weight transposes in one launch
  prep<<<dim3(4544), 256, 0, stream>>>(x, xb, Wkv, WkT, WvT, Wq, Wq_t, Wp, Wp_t);

  // fused K/V/Q projection (R12: 64 KB LDS, 2 blocks/CU)
  qkv_fused<<<dim3(1536), 512, 0, stream>>>(xb, WkT,
      bkv, g_kv, b_kv, m_kv, v_kv, bq, g_q, b_q, m_q, v_q,
      Kbuf, Vtb, Qbuf);

  attn_kernel<<<dim3(512), 256, 0, stream>>>(Qbuf, Kbuf, Vtb, outp);

  // fused output projection
  proj_fused<<<dim3(256), 512, 0, stream>>>(outp, Wp_t, bp, g_p, b_p, m_p, v_p, (float*)d_out);
}